// Round 1
// 433.697 us; speedup vs baseline: 1.0525x; 1.0525x over previous
//
#include <hip/hip_runtime.h>

#define D_IMG  1024
#define K_DIM  3
#define O_IMG  1022          // D - K + 1
#define RPT    14            // 73 strips * 14 rows == 1022 exactly -> no tail
#define STRIPS 73
#define NXCD   8

__global__ __launch_bounds__(256) void conv3x3_kernel(
    const float* __restrict__ in,   // [B, D, D]
    const float* __restrict__ w,    // [3,3]
    float* __restrict__ out)        // [B, O, O]
{
    // XCD-aware chunked swizzle: grid = 64*73 = 4672 = 8*584 (bijective).
    // Consecutive strips of one image land on the SAME XCD -> the 2-row
    // strip overlap becomes an L2 hit instead of an HBM re-fetch.
    int bid = blockIdx.x;
    {
        const int nwg = 64 * STRIPS;   // 4672
        const int cpx = nwg / NXCD;    // 584
        bid = (bid % NXCD) * cpx + bid / NXCD;
    }
    const int img   = bid / STRIPS;
    const int strip = bid % STRIPS;
    const int y0    = strip * RPT;
    // Clamp lane 255 (x0=1020 -> 1018): duplicates lane 254's last 2 outputs
    // with identical values; keeps every load in-bounds (max idx x0+5 = 1023).
    const int x0    = min((int)threadIdx.x * 4, O_IMG - 4);

    const float* ip = in  + (size_t)img * ((size_t)D_IMG * D_IMG);
    float*       op = out + (size_t)img * ((size_t)O_IMG * O_IMG);

    // kernel weights: uniform indices -> scalar loads
    const float k00 = w[0], k01 = w[1], k02 = w[2];
    const float k10 = w[3], k11 = w[4], k12 = w[5];
    const float k20 = w[6], k21 = w[7], k22 = w[8];

    // rolling 3-row window, 6 floats per row (exactly what 4 outputs need)
    float r[3][6];

    auto loadrow = [&](int y, float* dst) {
        const float* p = ip + (size_t)y * D_IMG + x0;
        const float4 a = *(const float4*)(p);       // 16B aligned (x0 % 4 == 0 or 1018 -> %2; 1018*4=4072, 8B aligned OK for float4? no -> see note)
        const float2 b = *(const float2*)(p + 4);   // 16B aligned
        dst[0] = a.x; dst[1] = a.y; dst[2] = a.z; dst[3] = a.w;
        dst[4] = b.x; dst[5] = b.y;
    };
    // note on alignment: x0 is a multiple of 4 floats (16B) for all lanes
    // except the clamped lane 255 where x0=1018 (8B aligned). gfx950
    // global_load_dwordx4 requires only dword alignment, so this is safe.

    loadrow(y0,     r[0]);
    loadrow(y0 + 1, r[1]);

    // Fixed trip count, no break -> guaranteed full unroll, every r[][]
    // index is a compile-time constant (no scratch demotion).
    #pragma unroll
    for (int i = 0; i < RPT; ++i) {
        const int y = y0 + i;
        loadrow(y + 2, r[(i + 2) % 3]);   // max row read = 1021+2 = 1023, in range

        const float* a = r[(i + 0) % 3];
        const float* b = r[(i + 1) % 3];
        const float* c = r[(i + 2) % 3];

        float acc[4];
        #pragma unroll
        for (int j = 0; j < 4; ++j) {
            acc[j] = a[j] * k00 + a[j+1] * k01 + a[j+2] * k02
                   + b[j] * k10 + b[j+1] * k11 + b[j+2] * k12
                   + c[j] * k20 + c[j+1] * k21 + c[j+2] * k22;
        }

        // output row stride 4088 B: odd rows are only 8B-aligned -> float2 x2
        float* orow = op + (size_t)y * O_IMG + x0;
        *(float2*)(orow + 0) = make_float2(acc[0], acc[1]);
        *(float2*)(orow + 2) = make_float2(acc[2], acc[3]);
    }
}

extern "C" void kernel_launch(void* const* d_in, const int* in_sizes, int n_in,
                              void* d_out, int out_size, void* d_ws, size_t ws_size,
                              hipStream_t stream) {
    const float* in = (const float*)d_in[0];   // [64, 1024*1024] fp32
    const float* w  = (const float*)d_in[1];   // [3,3] fp32
    float* out      = (float*)d_out;           // [64, 1022*1022] fp32

    const int B = 64;
    dim3 grid(B * STRIPS);   // 4672 blocks
    dim3 block(256);
    conv3x3_kernel<<<grid, block, 0, stream>>>(in, w, out);
}